// Round 6
// baseline (187.630 us; speedup 1.0000x reference)
//
#include <hip/hip_runtime.h>
#include <hip/hip_bf16.h>
#include <math.h>

#define B_TOT 16384
#define NPART 16
#define NPAIR 120     // 16*15/2
#define HID   64
#define DL    5
#define GB    4       // 4 waves/block, wave w <-> batch bg+w (fully independent)
#define SROWS 136     // per-wave s_f rows: 0..119 psi pairs, 120..135 phi

typedef __attribute__((ext_vector_type(8))) short short8;
typedef __attribute__((ext_vector_type(4))) float floatx4;

// Scale-fold constant: c = 1.702 * log2(e). Layer-1 W,b pre-scaled by c,
// layer-2 bias by c, 1/c folded into the readout column sums.
#define CSC      2.45556851f
#define INV_CSC  0.40723744f

// Single-instruction packed f32->bf16 convert (RNE).
__device__ __forceinline__ unsigned pk2(float a, float b) {
    unsigned r;
    asm("v_cvt_pk_bf16_f32 %0, %1, %2" : "=v"(r) : "v"(a), "v"(b));
    return r;
}

// pre-scaled gelu: input z = CSC * (true preact); returns CSC * gelu(true).
__device__ __forceinline__ float gelu_pre(float z) {
    float e = __builtin_amdgcn_exp2f(-z);
    return z * __builtin_amdgcn_rcpf(1.0f + e);
}

// unfolded form, used once in the rho readout only
__device__ __forceinline__ float gelu_sig(float v) {
    float e = __builtin_amdgcn_exp2f(-2.45556851f * v);
    return v * __builtin_amdgcn_rcpf(1.0f + e);
}

__device__ __forceinline__ float wred(float v) {
    v += __shfl_down(v, 32);
    v += __shfl_down(v, 16);
    v += __shfl_down(v, 8);
    v += __shfl_down(v, 4);
    v += __shfl_down(v, 2);
    v += __shfl_down(v, 1);
    return v;
}

// hidden-row permutation: tile ht, MFMA row m -> hidden index.
// Chosen so phase-1 D-frag lane (q,m15) holds exactly hiddens {q*8..q*8+7}
// (ht 0,1) and {32+q*8..+7} (ht 2,3) of M-row m15 -- i.e. precisely the
// k-slots its own phase-2 B-fragment needs. h1 never touches LDS.
__device__ __forceinline__ int hperm(int ht, int m) {
    return ((ht & 1) << 2) + ((ht >> 1) << 5) + ((m >> 2) << 3) + (m & 3);
}

// R16 (resubmit; R5 bench died to container infra, kernel re-audited clean):
//  - swapped phase-1 (A = permuted W0 rows, B = feature rows), permuted W1
//    K-order identical -> phase-2 B-frags are LANE-LOCAL register data
//  - NO s_h, NO __syncthreads anywhere; LDS = per-wave features (8.7KB) +
//    2KB colsum staging only
//  - layer-1 bias folded into feature slot k=6 (psi) / k=3 (phi) as 1.0
//  - colsum: 16 per-lane accs, xor-shuffle reduce over m15, predicated store
//  - VGPR-capped occupancy: __launch_bounds__(256,4) (<=128 VGPR)
__global__ __launch_bounds__(256, 4) void jastrow_wave(
    const float* __restrict__ x,
    const float* __restrict__ phi_w0, const float* __restrict__ phi_b0,
    const float* __restrict__ phi_w1, const float* __restrict__ phi_b1,
    const float* __restrict__ phi_w2, const float* __restrict__ phi_b2,
    const float* __restrict__ psi_w0, const float* __restrict__ psi_b0,
    const float* __restrict__ psi_w1, const float* __restrict__ psi_b1,
    const float* __restrict__ psi_w2, const float* __restrict__ psi_b2,
    const float* __restrict__ rho_w0, const float* __restrict__ rho_b0,
    const float* __restrict__ rho_w1, const float* __restrict__ rho_b1,
    float* __restrict__ out)
{
    const int t    = threadIdx.x;
    const int lane = t & 63;
    const int wv   = t >> 6;
    const int q    = lane >> 4;
    const int m15  = lane & 15;
    const int bg   = blockIdx.x * GB;

    __shared__ __align__(16) unsigned short s_f[GB * SROWS * 8];  // 8704 B
    __shared__ float s_cs[GB * 2 * HID];                          // 2048 B
    unsigned short* sf = s_f + wv * SROWS * 8;

    const float2* x2 = (const float2*)x;
    const int bi = bg + wv;          // this wave's batch element
    float cusp = 0.f;

    // ================= Phase 0: features -> per-wave s_f ======================
    {
        {
            int p = lane;                     // 0..63
            int u = 119 - p;
            float sq = sqrtf((float)(8 * u + 1));
            int k = (int)((sq - 1.0f) * 0.5f);
            int i = 14 - k;
            int j = p - (i * (31 - i)) / 2 + i + 1;

            float2 xi = x2[bi * NPART + i];
            float2 xj = x2[bi * NPART + j];
            float dx = xi.x - xj.x, dy = xi.y - xj.y;
            float r = sqrtf(dx * dx + dy * dy + 1e-12f);

            float f0 = 0.69314718056f * __builtin_amdgcn_logf(1.f + r);
            float f1 = r * __builtin_amdgcn_rcpf(1.f + r);
            float f3 = __builtin_amdgcn_exp2f(-0.72134752044f * r);
            float f4 = f3 * f3;
            float f5 = f4 * f4;
            float f2 = __builtin_amdgcn_exp2f(-1.44269504089f * r * r);
            cusp += r * f4;                   // exact fp32

            union { short8 s; unsigned u4[4]; } v;
            v.u4[0] = pk2(f0, f1);
            v.u4[1] = pk2(f2, f3);
            v.u4[2] = pk2(f4, f5);
            v.u4[3] = pk2(1.0f, 0.f);         // k6 = 1.0 (bias slot), k7 = 0
            *(short8*)&sf[p * 8] = v.s;
        }
        if (lane < NPAIR - 64) {              // 56 more pairs
            int p = 64 + lane;
            int u = 119 - p;
            float sq = sqrtf((float)(8 * u + 1));
            int k = (int)((sq - 1.0f) * 0.5f);
            int i = 14 - k;
            int j = p - (i * (31 - i)) / 2 + i + 1;

            float2 xi = x2[bi * NPART + i];
            float2 xj = x2[bi * NPART + j];
            float dx = xi.x - xj.x, dy = xi.y - xj.y;
            float r = sqrtf(dx * dx + dy * dy + 1e-12f);

            float f0 = 0.69314718056f * __builtin_amdgcn_logf(1.f + r);
            float f1 = r * __builtin_amdgcn_rcpf(1.f + r);
            float f3 = __builtin_amdgcn_exp2f(-0.72134752044f * r);
            float f4 = f3 * f3;
            float f5 = f4 * f4;
            float f2 = __builtin_amdgcn_exp2f(-1.44269504089f * r * r);
            cusp += r * f4;

            union { short8 s; unsigned u4[4]; } v;
            v.u4[0] = pk2(f0, f1);
            v.u4[1] = pk2(f2, f3);
            v.u4[2] = pk2(f4, f5);
            v.u4[3] = pk2(1.0f, 0.f);
            *(short8*)&sf[p * 8] = v.s;
        }
        if (lane >= 48) {                     // 16 phi rows
            int n = lane - 48;
            float2 xv = x2[bi * NPART + n];
            float r2 = xv.x * xv.x + xv.y * xv.y;
            union { short8 s; unsigned u4[4]; } w;
            w.u4[0] = pk2(xv.x, xv.y);
            w.u4[1] = pk2(r2, 1.0f);          // k3 = 1.0 (bias slot)
            w.u4[2] = 0u; w.u4[3] = 0u;
            *(short8*)&sf[(120 + n) * 8] = w.s;
        }
    }
    float cusp_b;
    { float cc = wred(cusp); cusp_b = __shfl(cc, 0); }

    const floatx4 zf4 = {0.f, 0.f, 0.f, 0.f};

    // --------- psi fragments (permuted rows) ----------------------------------
    // A1p[ht]: q==0 lanes: W0 row hperm(ht,m15), k0..5 = CSC*w, k6 = CSC*b0.
    short8 A1p[4];
#pragma unroll
    for (int ht = 0; ht < 4; ++ht) {
        short8 f = (short8)0;
        if (q == 0) {
            int h = hperm(ht, m15);
            const float* w = psi_w0 + h * 6;
            union { short8 s; unsigned u4[4]; } bb;
            bb.u4[0] = pk2(CSC * w[0], CSC * w[1]);
            bb.u4[1] = pk2(CSC * w[2], CSC * w[3]);
            bb.u4[2] = pk2(CSC * w[4], CSC * w[5]);
            bb.u4[3] = pk2(CSC * psi_b0[h], 0.f);
            f = bb.s;
        }
        A1p[ht] = f;
    }
    // A2p[ht2][ks]: W1 row hperm(ht2,m15), k-slots = hidden (ks*32 + q*8 + j)
    // (identity in permuted hidden order). C1p[ht2] = CSC * b1 (permuted).
    short8 A2p[4][2];
    floatx4 C1p[4];
#pragma unroll
    for (int ht2 = 0; ht2 < 4; ++ht2) {
        int h2 = hperm(ht2, m15);
#pragma unroll
        for (int ks = 0; ks < 2; ++ks) {
            const floatx4* wp = (const floatx4*)(psi_w1 + h2 * HID + ks * 32 + q * 8);
            floatx4 wa = wp[0], wb = wp[1];
            union { short8 s; unsigned u4[4]; } bb;
            bb.u4[0] = pk2(wa[0], wa[1]); bb.u4[1] = pk2(wa[2], wa[3]);
            bb.u4[2] = pk2(wb[0], wb[1]); bb.u4[3] = pk2(wb[2], wb[3]);
            A2p[ht2][ks] = bb.s;
        }
        int cb = ((ht2 & 1) << 2) + ((ht2 >> 1) << 5) + (q << 3);
        floatx4 bv = *(const floatx4*)(psi_b1 + cb);
        C1p[ht2] = bv * CSC;
    }

    float CS[16];
#pragma unroll
    for (int i = 0; i < 16; ++i) CS[i] = 0.f;

    // ================= psi: 8 M-tiles, all in registers =======================
#pragma unroll
    for (int Mt = 0; Mt < 8; ++Mt) {
        short8 b = *(const short8*)&sf[(Mt * 16 + m15) * 8];
        floatx4 d0 = __builtin_amdgcn_mfma_f32_16x16x32_bf16(A1p[0], b, zf4, 0, 0, 0);
        floatx4 d1 = __builtin_amdgcn_mfma_f32_16x16x32_bf16(A1p[1], b, zf4, 0, 0, 0);
        union { short8 s; unsigned u4[4]; } Bk0, Bk1;
        Bk0.u4[0] = pk2(gelu_pre(d0[0]), gelu_pre(d0[1]));
        Bk0.u4[1] = pk2(gelu_pre(d0[2]), gelu_pre(d0[3]));
        Bk0.u4[2] = pk2(gelu_pre(d1[0]), gelu_pre(d1[1]));
        Bk0.u4[3] = pk2(gelu_pre(d1[2]), gelu_pre(d1[3]));
        floatx4 d2 = __builtin_amdgcn_mfma_f32_16x16x32_bf16(A1p[2], b, zf4, 0, 0, 0);
        floatx4 d3 = __builtin_amdgcn_mfma_f32_16x16x32_bf16(A1p[3], b, zf4, 0, 0, 0);
        Bk1.u4[0] = pk2(gelu_pre(d2[0]), gelu_pre(d2[1]));
        Bk1.u4[1] = pk2(gelu_pre(d2[2]), gelu_pre(d2[3]));
        Bk1.u4[2] = pk2(gelu_pre(d3[0]), gelu_pre(d3[1]));
        Bk1.u4[3] = pk2(gelu_pre(d3[2]), gelu_pre(d3[3]));

#pragma unroll
        for (int ht2 = 0; ht2 < 4; ++ht2) {
            floatx4 acc = __builtin_amdgcn_mfma_f32_16x16x32_bf16(A2p[ht2][0], Bk0.s, C1p[ht2], 0, 0, 0);
            acc = __builtin_amdgcn_mfma_f32_16x16x32_bf16(A2p[ht2][1], Bk1.s, acc, 0, 0, 0);
#pragma unroll
            for (int rg = 0; rg < 4; ++rg) {
                float z = acc[rg];
                float rr = __builtin_amdgcn_rcpf(1.0f + __builtin_amdgcn_exp2f(-z));
                if (Mt == 7) {
                    float p = z * rr;
                    p = (m15 < 8) ? p : 0.f;   // ghost M-rows 120..127
                    CS[ht2 * 4 + rg] += p;
                } else {
                    CS[ht2 * 4 + rg] = __builtin_fmaf(z, rr, CS[ht2 * 4 + rg]);
                }
            }
        }
    }

    // reduce colsums over the 16 m15 lanes (stays within each q-group)
#pragma unroll
    for (int i = 0; i < 16; ++i) {
        CS[i] += __shfl_xor(CS[i], 1);
        CS[i] += __shfl_xor(CS[i], 2);
        CS[i] += __shfl_xor(CS[i], 4);
        CS[i] += __shfl_xor(CS[i], 8);
    }
    // predicated store: lane m15==i writes CS[i] at its hidden2 index
#pragma unroll
    for (int i = 0; i < 16; ++i) {
        if (m15 == i) {
            int h2 = ((i >> 2) & 1) * 4 + (i >> 3) * 32 + q * 8 + (i & 3);
            s_cs[(wv * 2 + 0) * HID + h2] = CS[i];
        }
    }

    __builtin_amdgcn_sched_barrier(0);   // keep phi frag loads after psi loop

    // ================= phi: 1 M-tile (s_f rows 120..135) ======================
    {
        short8 A1f[4];
#pragma unroll
        for (int ht = 0; ht < 4; ++ht) {
            short8 f = (short8)0;
            if (q == 0) {
                int h = hperm(ht, m15);
                const float* w = phi_w0 + h * 3;
                union { short8 s; unsigned u4[4]; } bb;
                bb.u4[0] = pk2(CSC * w[0], CSC * w[1]);
                bb.u4[1] = pk2(CSC * w[2], CSC * phi_b0[h]);  // k3 = bias
                bb.u4[2] = 0u; bb.u4[3] = 0u;
                f = bb.s;
            }
            A1f[ht] = f;
        }
        short8 A2f[4][2];
        floatx4 C1f[4];
#pragma unroll
        for (int ht2 = 0; ht2 < 4; ++ht2) {
            int h2 = hperm(ht2, m15);
#pragma unroll
            for (int ks = 0; ks < 2; ++ks) {
                const floatx4* wp = (const floatx4*)(phi_w1 + h2 * HID + ks * 32 + q * 8);
                floatx4 wa = wp[0], wb = wp[1];
                union { short8 s; unsigned u4[4]; } bb;
                bb.u4[0] = pk2(wa[0], wa[1]); bb.u4[1] = pk2(wa[2], wa[3]);
                bb.u4[2] = pk2(wb[0], wb[1]); bb.u4[3] = pk2(wb[2], wb[3]);
                A2f[ht2][ks] = bb.s;
            }
            int cb = ((ht2 & 1) << 2) + ((ht2 >> 1) << 5) + (q << 3);
            floatx4 bv = *(const floatx4*)(phi_b1 + cb);
            C1f[ht2] = bv * CSC;
        }

        float CF[16];
        short8 b = *(const short8*)&sf[(120 + m15) * 8];
        floatx4 d0 = __builtin_amdgcn_mfma_f32_16x16x32_bf16(A1f[0], b, zf4, 0, 0, 0);
        floatx4 d1 = __builtin_amdgcn_mfma_f32_16x16x32_bf16(A1f[1], b, zf4, 0, 0, 0);
        union { short8 s; unsigned u4[4]; } Bk0, Bk1;
        Bk0.u4[0] = pk2(gelu_pre(d0[0]), gelu_pre(d0[1]));
        Bk0.u4[1] = pk2(gelu_pre(d0[2]), gelu_pre(d0[3]));
        Bk0.u4[2] = pk2(gelu_pre(d1[0]), gelu_pre(d1[1]));
        Bk0.u4[3] = pk2(gelu_pre(d1[2]), gelu_pre(d1[3]));
        floatx4 d2 = __builtin_amdgcn_mfma_f32_16x16x32_bf16(A1f[2], b, zf4, 0, 0, 0);
        floatx4 d3 = __builtin_amdgcn_mfma_f32_16x16x32_bf16(A1f[3], b, zf4, 0, 0, 0);
        Bk1.u4[0] = pk2(gelu_pre(d2[0]), gelu_pre(d2[1]));
        Bk1.u4[1] = pk2(gelu_pre(d2[2]), gelu_pre(d2[3]));
        Bk1.u4[2] = pk2(gelu_pre(d3[0]), gelu_pre(d3[1]));
        Bk1.u4[3] = pk2(gelu_pre(d3[2]), gelu_pre(d3[3]));

#pragma unroll
        for (int ht2 = 0; ht2 < 4; ++ht2) {
            floatx4 acc = __builtin_amdgcn_mfma_f32_16x16x32_bf16(A2f[ht2][0], Bk0.s, C1f[ht2], 0, 0, 0);
            acc = __builtin_amdgcn_mfma_f32_16x16x32_bf16(A2f[ht2][1], Bk1.s, acc, 0, 0, 0);
#pragma unroll
            for (int rg = 0; rg < 4; ++rg) {
                float z = acc[rg];
                float rr = __builtin_amdgcn_rcpf(1.0f + __builtin_amdgcn_exp2f(-z));
                CF[ht2 * 4 + rg] = z * rr;
            }
        }
#pragma unroll
        for (int i = 0; i < 16; ++i) {
            CF[i] += __shfl_xor(CF[i], 1);
            CF[i] += __shfl_xor(CF[i], 2);
            CF[i] += __shfl_xor(CF[i], 4);
            CF[i] += __shfl_xor(CF[i], 8);
        }
#pragma unroll
        for (int i = 0; i < 16; ++i) {
            if (m15 == i) {
                int h2 = ((i >> 2) & 1) * 4 + (i >> 3) * 32 + q * 8 + (i & 3);
                s_cs[(wv * 2 + 1) * HID + h2] = CF[i];
            }
        }
    }

    // ================= readout (per wave; same-wave LDS, no barrier) ==========
    {
        const int c = lane;
        float colP = s_cs[(wv * 2 + 0) * HID + c] * INV_CSC;
        float colF = s_cs[(wv * 2 + 1) * HID + c] * INV_CSC;

        float psiv[DL], phiv[DL];
#pragma unroll
        for (int d = 0; d < DL; ++d) {
            float sP = wred(colP * psi_w2[d * HID + c]);
            psiv[d] = __shfl(sP, 0) * (1.0f / NPAIR) + psi_b2[d];
            float sF = wred(colF * phi_w2[d * HID + c]);
            phiv[d] = __shfl(sF, 0) * (1.0f / NPART) + phi_b2[d];
        }

        int j = lane;
        float a = rho_b0[j];
        const float* wr = rho_w0 + j * (2 * DL);
#pragma unroll
        for (int d = 0; d < DL; ++d)
            a += phiv[d] * wr[d] + psiv[d] * wr[DL + d];
        float cv = gelu_sig(a) * rho_w1[j];
        cv = wred(cv);
        if (j == 0) out[bi] = cv + rho_b1[0] + cusp_b;
    }
}

extern "C" void kernel_launch(void* const* d_in, const int* in_sizes, int n_in,
                              void* d_out, int out_size, void* d_ws, size_t ws_size,
                              hipStream_t stream) {
    const float* x      = (const float*)d_in[0];
    const float* phi_w0 = (const float*)d_in[1];
    const float* phi_b0 = (const float*)d_in[2];
    const float* phi_w1 = (const float*)d_in[3];
    const float* phi_b1 = (const float*)d_in[4];
    const float* phi_w2 = (const float*)d_in[5];
    const float* phi_b2 = (const float*)d_in[6];
    const float* psi_w0 = (const float*)d_in[7];
    const float* psi_b0 = (const float*)d_in[8];
    const float* psi_w1 = (const float*)d_in[9];
    const float* psi_b1 = (const float*)d_in[10];
    const float* psi_w2 = (const float*)d_in[11];
    const float* psi_b2 = (const float*)d_in[12];
    const float* rho_w0 = (const float*)d_in[13];
    const float* rho_b0 = (const float*)d_in[14];
    const float* rho_w1 = (const float*)d_in[15];
    const float* rho_b1 = (const float*)d_in[16];

    jastrow_wave<<<B_TOT / GB, 256, 0, stream>>>(
        x,
        phi_w0, phi_b0, phi_w1, phi_b1, phi_w2, phi_b2,
        psi_w0, psi_b0, psi_w1, psi_b1, psi_w2, psi_b2,
        rho_w0, rho_b0, rho_w1, rho_b1,
        (float*)d_out);
}